// Round 3
// baseline (281.488 us; speedup 1.0000x reference)
//
#include <hip/hip_runtime.h>
#include <stdint.h>

#define EPS 1e-3f

typedef __bf16 bf16x8 __attribute__((ext_vector_type(8)));
typedef float  f32x4  __attribute__((ext_vector_type(4)));

static __device__ __forceinline__ uint16_t f2bf(float f) {
  union { float f; uint32_t u; } v; v.f = f;
  uint32_t u = v.u;
  uint32_t r = u + 0x7fffu + ((u >> 16) & 1u);   // RNE
  return (uint16_t)(r >> 16);
}
static __device__ __forceinline__ void gload_lds16(const void* g, void* l) {
  __builtin_amdgcn_global_load_lds(
      (const __attribute__((address_space(1))) unsigned int*)g,
      (__attribute__((address_space(3))) unsigned int*)l, 16, 0, 0);
}

// ---------------------------------------------------------------------------
// Kernel 1: E convert+transpose.  E:[n][m][16] f32 -> Ebf:[n*16+k][m] bf16
// (round-1 version, known good)
// ---------------------------------------------------------------------------
__global__ __launch_bounds__(256) void econv(const float* __restrict__ E,
                                             uint16_t* __restrict__ Ebf)
{
  const int n = blockIdx.x, t = threadIdx.x;
  const float* En = E + (size_t)n * 16384;
#pragma unroll 1
  for (int kq = 0; kq < 4; ++kq) {
#pragma unroll
    for (int mi = 0; mi < 4; ++mi) {
      int m = mi * 256 + t;
      float4 d = *(const float4*)&En[m * 16 + kq * 4];
      const float* dp = (const float*)&d;
#pragma unroll
      for (int j = 0; j < 4; ++j) {
        int k = kq * 4 + j;
        Ebf[(size_t)(n * 16 + k) * 1024 + m] = f2bf(dp[j]);
      }
    }
  }
}

// ---------------------------------------------------------------------------
// Kernel 2: fused projections + BN + softmax + V-transpose + lam_c partials.
// Block = (b, mc): 32 rows (m = mc*32..+31) of batch b.
// Outputs: Qf [16384][64] f32, VbfT [b*64+v][1024] bf16,
//          part [b][mc][16k][64v] f32.   Ksm/Vf never hit HBM.
// ---------------------------------------------------------------------------
__global__ __launch_bounds__(256) void proj_fused(
    const float* __restrict__ x, const float* __restrict__ Wq,
    const float* __restrict__ Wk, const float* __restrict__ Wv,
    const float* __restrict__ gq, const float* __restrict__ bq,
    const float* __restrict__ mq, const float* __restrict__ vq,
    const float* __restrict__ gv, const float* __restrict__ bv,
    const float* __restrict__ mv, const float* __restrict__ vvp,
    float* __restrict__ Qf, uint16_t* __restrict__ VbfT,
    float* __restrict__ part)
{
  __shared__ float xs[32 * 260];   // 33.3 KB, reused for vt/ks after compute
  const int t = threadIdx.x;
  const int b = blockIdx.x >> 5, mc = blockIdx.x & 31;
  const int r0 = b * 1024 + mc * 32;
#pragma unroll
  for (int it = 0; it < 8; ++it) {
    int f = it * 256 + t;
    int row = f >> 6, c4 = f & 63;
    *(float4*)&xs[row * 260 + c4 * 4] =
        *(const float4*)&x[(size_t)(r0 + row) * 256 + c4 * 4];
  }
  __syncthreads();
  const int rg = t >> 4, ci = t & 15;
  const float* xr = xs + rg * 2 * 260;

  float aq[2][4], ak[2], av[2][4];
#pragma unroll
  for (int rr = 0; rr < 2; ++rr) {
    ak[rr] = 0.f;
#pragma unroll
    for (int j = 0; j < 4; ++j) { aq[rr][j] = 0.f; av[rr][j] = 0.f; }
  }
#pragma unroll 2
  for (int m = 0; m < 256; ++m) {
    float w0 = Wq[m * 64 + ci];
    float w1 = Wq[m * 64 + ci + 16];
    float w2 = Wq[m * 64 + ci + 32];
    float w3 = Wq[m * 64 + ci + 48];
    float wk = Wk[m * 16 + ci];
    float u0 = Wv[m * 64 + ci];
    float u1 = Wv[m * 64 + ci + 16];
    float u2 = Wv[m * 64 + ci + 32];
    float u3 = Wv[m * 64 + ci + 48];
#pragma unroll
    for (int rr = 0; rr < 2; ++rr) {
      float xv = xr[rr * 260 + m];
      aq[rr][0] = fmaf(xv, w0, aq[rr][0]);
      aq[rr][1] = fmaf(xv, w1, aq[rr][1]);
      aq[rr][2] = fmaf(xv, w2, aq[rr][2]);
      aq[rr][3] = fmaf(xv, w3, aq[rr][3]);
      ak[rr]    = fmaf(xv, wk, ak[rr]);
      av[rr][0] = fmaf(xv, u0, av[rr][0]);
      av[rr][1] = fmaf(xv, u1, av[rr][1]);
      av[rr][2] = fmaf(xv, u2, av[rr][2]);
      av[rr][3] = fmaf(xv, u3, av[rr][3]);
    }
  }

  float sqv[4], bqv[4], mqv[4], svv[4], bvv[4], mvv[4];
#pragma unroll
  for (int j = 0; j < 4; ++j) {
    int c = ci + 16 * j;
    sqv[j] = gq[c] * rsqrtf(vq[c] + EPS); bqv[j] = bq[c]; mqv[j] = mq[c];
    svv[j] = gv[c] * rsqrtf(vvp[c] + EPS); bvv[j] = bv[c]; mvv[j] = mv[c];
  }

  // Q out + softmax values + BN'd v, staged for reuse
  float kout[2], vout[2][4];
#pragma unroll
  for (int rr = 0; rr < 2; ++rr) {
    const int r = r0 + rg * 2 + rr;
#pragma unroll
    for (int j = 0; j < 4; ++j)
      Qf[(size_t)r * 64 + ci + 16 * j] = (aq[rr][j] - mqv[j]) * sqv[j] + bqv[j];
    float kv = ak[rr];
    float mx = kv;
#pragma unroll
    for (int d = 1; d < 16; d <<= 1) mx = fmaxf(mx, __shfl_xor(mx, d, 64));
    float e = __expf(kv - mx);
    float sm = e;
#pragma unroll
    for (int d = 1; d < 16; d <<= 1) sm += __shfl_xor(sm, d, 64);
    kout[rr] = e / sm;
#pragma unroll
    for (int j = 0; j < 4; ++j)
      vout[rr][j] = (av[rr][j] - mvv[j]) * svv[j] + bvv[j];
  }

  __syncthreads();   // done with xs as x-tile
  float* vt = xs;               // [32][65]
  float* ks = xs + 32 * 65;     // [32][20]
#pragma unroll
  for (int rr = 0; rr < 2; ++rr) {
    const int rl = rg * 2 + rr;
    ks[rl * 20 + ci] = kout[rr];
#pragma unroll
    for (int j = 0; j < 4; ++j) vt[rl * 65 + ci + 16 * j] = vout[rr][j];
  }
  __syncthreads();

  // V transpose -> VbfT (16B stores)
  {
    const int v = t & 63, grp = t >> 6;
    union { uint16_t u16[8]; uint4 u4; } pk;
#pragma unroll
    for (int i = 0; i < 8; ++i) pk.u16[i] = f2bf(vt[(grp * 8 + i) * 65 + v]);
    *(uint4*)&VbfT[(size_t)(b * 64 + v) * 1024 + mc * 32 + grp * 8] = pk.u4;
  }
  // lam_c partial for this (b, mc)
  {
    const int kq = t >> 6, v = t & 63;
    float a0 = 0.f, a1 = 0.f, a2 = 0.f, a3 = 0.f;
#pragma unroll 4
    for (int m = 0; m < 32; ++m) {
      float vv = vt[m * 65 + v];
      a0 = fmaf(ks[m * 20 + kq * 4 + 0], vv, a0);
      a1 = fmaf(ks[m * 20 + kq * 4 + 1], vv, a1);
      a2 = fmaf(ks[m * 20 + kq * 4 + 2], vv, a2);
      a3 = fmaf(ks[m * 20 + kq * 4 + 3], vv, a3);
    }
    float* dst = part + ((size_t)(b * 32 + mc) << 10) + (kq * 4) * 64 + v;
    dst[0] = a0; dst[64] = a1; dst[128] = a2; dst[192] = a3;
  }
}

// Kernel 3: reduce 32 partials -> Lc[b][k][v]
__global__ __launch_bounds__(256) void lamc_reduce(const float* __restrict__ part,
                                                   float* __restrict__ Lc)
{
  const int gid = blockIdx.x * 256 + threadIdx.x;   // 0..16383
  const int b = gid >> 10, r = gid & 1023;
  const float* p = part + ((size_t)b << 15) + r;    // b*32*1024
  float s = 0.f;
#pragma unroll
  for (int mc = 0; mc < 32; ++mc) s += p[mc << 10];
  Lc[((size_t)b << 10) + r] = s;
}

// ---------------------------------------------------------------------------
// Kernel 4: GEMM C[row=n*16+k][col=b*64+v] = Ebf . VbfT^T (both bf16, both
// staged by global_load_lds). 256x256 tile, BK=64, 8 waves (2x4), double
// buffer, prefetch-before-compute, single barrier/tile, XOR swizzle, XCD map.
// Fused epilogue: out = Q-contraction of (C + Lc).
// ---------------------------------------------------------------------------
__global__ __launch_bounds__(512, 2) void gemm_out(
    const uint16_t* __restrict__ Ebf,   // [16384][1024]
    const uint16_t* __restrict__ VbfT,  // [1024][1024]
    const float* __restrict__ Qf,       // [16384][64]
    const float* __restrict__ Lc,       // [16][16][64]
    float* __restrict__ out)            // [16384][256]
{
  __shared__ __align__(16) char smem[131072];
  char* const A0 = smem;
  char* const B0 = smem + 32768;
  char* const A1 = smem + 65536;
  char* const B1 = smem + 98304;

  const int t = threadIdx.x;
  const int wid = t >> 6, lane = t & 63;
  const int wm = wid >> 2, wn = wid & 3;
  const int bid = blockIdx.x;
  const int xcd = bid & 7, idx = bid >> 3;
  const int rb = xcd * 8 + (idx >> 2);   // 0..63
  const int cb = idx & 3;                // 0..3
  const int row0 = rb * 256;
  const int col0 = cb * 256;

  // per-thread staging addresses (4 A + 4 B loads of 16B per K-tile)
  const uint16_t* aptr[4];
  const uint16_t* bptr[4];
  int dst[4];
  {
    const uint16_t* Ab = Ebf + ((size_t)row0 << 10);
    const uint16_t* Bb = VbfT + ((size_t)col0 << 10);
#pragma unroll
    for (int it = 0; it < 4; ++it) {
      int id = it * 512 + t;
      int row = id >> 3, seg = id & 7;
      int src = (row << 10) + ((seg ^ (row & 7)) << 3);
      aptr[it] = Ab + src;
      bptr[it] = Bb + src;
      dst[it] = id * 16;
    }
  }

  f32x4 acc[8][4];
#pragma unroll
  for (int i = 0; i < 8; ++i)
#pragma unroll
    for (int j = 0; j < 4; ++j) acc[i][j] = f32x4{0.f, 0.f, 0.f, 0.f};

  // prologue: stage tile 0
#pragma unroll
  for (int it = 0; it < 4; ++it) {
    gload_lds16(aptr[it], A0 + dst[it]);
    gload_lds16(bptr[it], B0 + dst[it]);
  }
  __syncthreads();

#pragma unroll 1
  for (int kt = 0; kt < 16; ++kt) {
    char* Ac = (kt & 1) ? A1 : A0;
    char* Bc = (kt & 1) ? B1 : B0;
    char* An = (kt & 1) ? A0 : A1;
    char* Bn = (kt & 1) ? B0 : B1;
    if (kt < 15) {
      const int off = (kt + 1) * 64;
#pragma unroll
      for (int it = 0; it < 4; ++it) {
        gload_lds16(aptr[it] + off, An + dst[it]);
        gload_lds16(bptr[it] + off, Bn + dst[it]);
      }
    }
    __builtin_amdgcn_s_setprio(1);
#pragma unroll
    for (int kk = 0; kk < 2; ++kk) {
      bf16x8 a[8], b[4];
      const int s = kk * 4 + (lane >> 4);
#pragma unroll
      for (int i = 0; i < 8; ++i) {
        int row = wm * 128 + i * 16 + (lane & 15);
        a[i] = *(const bf16x8*)(Ac + row * 128 + ((s ^ (row & 7)) << 4));
      }
#pragma unroll
      for (int j = 0; j < 4; ++j) {
        int row = wn * 64 + j * 16 + (lane & 15);
        b[j] = *(const bf16x8*)(Bc + row * 128 + ((s ^ (row & 7)) << 4));
      }
#pragma unroll
      for (int i = 0; i < 8; ++i)
#pragma unroll
        for (int j = 0; j < 4; ++j)
          acc[i][j] = __builtin_amdgcn_mfma_f32_16x16x32_bf16(a[i], b[j], acc[i][j], 0, 0, 0);
    }
    __builtin_amdgcn_s_setprio(0);
    __syncthreads();
  }

  // fused epilogue: 4 phases of 64 rows through LDS
  float* Cs = (float*)smem;        // [64][258] = 66 KB
  const int n0 = rb * 16;
  const int b0 = cb * 4;
#pragma unroll 1
  for (int p = 0; p < 4; ++p) {
    if (wm == (p >> 1)) {
#pragma unroll
      for (int il = 0; il < 4; ++il) {
        const int i = ((p & 1) << 2) + il;
#pragma unroll
        for (int j = 0; j < 4; ++j) {
          const int col = wn * 64 + j * 16 + (lane & 15);
          const int bb = b0 + (col >> 6), v = col & 63;
#pragma unroll
          for (int r = 0; r < 4; ++r) {
            const int rl = il * 16 + ((lane >> 4) << 2) + r;
            const int k = rl & 15;
            Cs[rl * 258 + col] = acc[i][j][r] + Lc[(size_t)(((bb << 4) + k) << 6) + v];
          }
        }
      }
    }
    __syncthreads();
    {
      const int v = t & 63;
#pragma unroll
      for (int c = 0; c < 8; ++c) {
        const int combo = (wid << 3) + c;               // 0..63
        const int n_l = combo >> 4;                     // 0..3
        const int b_l = (combo >> 2) & 3;               // 0..3
        const int h = combo & 3;
        const int n = n0 + (p << 2) + n_l;
        const int bb = b0 + b_l;
        const float* qp = Qf + (((size_t)(bb << 10) + n) << 6) + (h << 4);
        float sum = 0.f;
#pragma unroll
        for (int k = 0; k < 16; ++k)
          sum = fmaf(qp[k], Cs[((n_l << 4) + k) * 258 + (b_l << 6) + v], sum);
        out[(((size_t)(bb << 10) + n) << 8) + (h << 6) + v] = sum;
      }
    }
    __syncthreads();
  }
}

// ---------------------------------------------------------------------------
extern "C" void kernel_launch(void* const* d_in, const int* in_sizes, int n_in,
                              void* d_out, int out_size, void* d_ws, size_t ws_size,
                              hipStream_t stream) {
  const float* x   = (const float*)d_in[0];
  const float* Wq  = (const float*)d_in[1];
  const float* Wk  = (const float*)d_in[2];
  const float* Wv  = (const float*)d_in[3];
  const float* gq  = (const float*)d_in[4];
  const float* bq  = (const float*)d_in[5];
  const float* mq  = (const float*)d_in[6];
  const float* vq  = (const float*)d_in[7];
  const float* gv  = (const float*)d_in[8];
  const float* bv  = (const float*)d_in[9];
  const float* mv  = (const float*)d_in[10];
  const float* vvp = (const float*)d_in[11];
  const float* E   = (const float*)d_in[12];
  float* out = (float*)d_out;

  char* ws = (char*)d_ws;
  uint16_t* Ebf  = (uint16_t*)(ws);                          // 32 MB
  uint16_t* VbfT = (uint16_t*)(ws + 33554432);               //  2 MB
  float*    Qf   = (float*)(ws + 35651584);                  //  4 MB
  float*    part = (float*)(ws + 39845888);                  //  2 MB
  float*    Lc   = (float*)(ws + 41943040);                  // 64 KB

  hipLaunchKernelGGL(econv, dim3(1024), dim3(256), 0, stream, E, Ebf);
  hipLaunchKernelGGL(proj_fused, dim3(512), dim3(256), 0, stream, x, Wq, Wk, Wv,
                     gq, bq, mq, vq, gv, bv, mv, vvp, Qf, VbfT, part);
  hipLaunchKernelGGL(lamc_reduce, dim3(64), dim3(256), 0, stream, part, Lc);
  hipLaunchKernelGGL(gemm_out, dim3(256), dim3(512), 0, stream, Ebf, VbfT, Qf, Lc, out);
}

// Round 4
// 120.397 us; speedup vs baseline: 2.3380x; 2.3380x over previous
//
#include <hip/hip_runtime.h>
#include <stdint.h>

#define EPS 1e-3f

typedef __bf16 bf16x8 __attribute__((ext_vector_type(8)));
typedef float  f32x4  __attribute__((ext_vector_type(4)));

static __device__ __forceinline__ uint16_t f2bf(float f) {
  union { float f; uint32_t u; } v; v.f = f;
  uint32_t u = v.u;
  uint32_t r = u + 0x7fffu + ((u >> 16) & 1u);   // RNE
  return (uint16_t)(r >> 16);
}
static __device__ __forceinline__ void gload_lds16(const void* g, void* l) {
  __builtin_amdgcn_global_load_lds(
      (const __attribute__((address_space(1))) unsigned int*)g,
      (__attribute__((address_space(3))) unsigned int*)l, 16, 0, 0);
}

// ---------------------------------------------------------------------------
// Kernel 1: E convert+transpose.  E:[n][m][16] f32 -> Ebf:[n*16+k][m] bf16
// ---------------------------------------------------------------------------
__global__ __launch_bounds__(256) void econv(const float* __restrict__ E,
                                             uint16_t* __restrict__ Ebf)
{
  const int n = blockIdx.x, t = threadIdx.x;
  const float* En = E + (size_t)n * 16384;
#pragma unroll 1
  for (int kq = 0; kq < 4; ++kq) {
#pragma unroll
    for (int mi = 0; mi < 4; ++mi) {
      int m = mi * 256 + t;
      float4 d = *(const float4*)&En[m * 16 + kq * 4];
      const float* dp = (const float*)&d;
#pragma unroll
      for (int j = 0; j < 4; ++j) {
        int k = kq * 4 + j;
        Ebf[(size_t)(n * 16 + k) * 1024 + m] = f2bf(dp[j]);
      }
    }
  }
}

// ---------------------------------------------------------------------------
// Kernel 2: fused projections + BN + softmax + V-transpose + lam_c partials.
// ---------------------------------------------------------------------------
__global__ __launch_bounds__(256) void proj_fused(
    const float* __restrict__ x, const float* __restrict__ Wq,
    const float* __restrict__ Wk, const float* __restrict__ Wv,
    const float* __restrict__ gq, const float* __restrict__ bq,
    const float* __restrict__ mq, const float* __restrict__ vq,
    const float* __restrict__ gv, const float* __restrict__ bv,
    const float* __restrict__ mv, const float* __restrict__ vvp,
    float* __restrict__ Qf, uint16_t* __restrict__ VbfT,
    float* __restrict__ part)
{
  __shared__ float xs[32 * 260];
  const int t = threadIdx.x;
  const int b = blockIdx.x >> 5, mc = blockIdx.x & 31;
  const int r0 = b * 1024 + mc * 32;
#pragma unroll
  for (int it = 0; it < 8; ++it) {
    int f = it * 256 + t;
    int row = f >> 6, c4 = f & 63;
    *(float4*)&xs[row * 260 + c4 * 4] =
        *(const float4*)&x[(size_t)(r0 + row) * 256 + c4 * 4];
  }
  __syncthreads();
  const int rg = t >> 4, ci = t & 15;
  const float* xr = xs + rg * 2 * 260;

  float aq[2][4], ak[2], av[2][4];
#pragma unroll
  for (int rr = 0; rr < 2; ++rr) {
    ak[rr] = 0.f;
#pragma unroll
    for (int j = 0; j < 4; ++j) { aq[rr][j] = 0.f; av[rr][j] = 0.f; }
  }
#pragma unroll 2
  for (int m = 0; m < 256; ++m) {
    float w0 = Wq[m * 64 + ci];
    float w1 = Wq[m * 64 + ci + 16];
    float w2 = Wq[m * 64 + ci + 32];
    float w3 = Wq[m * 64 + ci + 48];
    float wk = Wk[m * 16 + ci];
    float u0 = Wv[m * 64 + ci];
    float u1 = Wv[m * 64 + ci + 16];
    float u2 = Wv[m * 64 + ci + 32];
    float u3 = Wv[m * 64 + ci + 48];
#pragma unroll
    for (int rr = 0; rr < 2; ++rr) {
      float xv = xr[rr * 260 + m];
      aq[rr][0] = fmaf(xv, w0, aq[rr][0]);
      aq[rr][1] = fmaf(xv, w1, aq[rr][1]);
      aq[rr][2] = fmaf(xv, w2, aq[rr][2]);
      aq[rr][3] = fmaf(xv, w3, aq[rr][3]);
      ak[rr]    = fmaf(xv, wk, ak[rr]);
      av[rr][0] = fmaf(xv, u0, av[rr][0]);
      av[rr][1] = fmaf(xv, u1, av[rr][1]);
      av[rr][2] = fmaf(xv, u2, av[rr][2]);
      av[rr][3] = fmaf(xv, u3, av[rr][3]);
    }
  }

  float sqv[4], bqv[4], mqv[4], svv[4], bvv[4], mvv[4];
#pragma unroll
  for (int j = 0; j < 4; ++j) {
    int c = ci + 16 * j;
    sqv[j] = gq[c] * rsqrtf(vq[c] + EPS); bqv[j] = bq[c]; mqv[j] = mq[c];
    svv[j] = gv[c] * rsqrtf(vvp[c] + EPS); bvv[j] = bv[c]; mvv[j] = mv[c];
  }

  float kout[2], vout[2][4];
#pragma unroll
  for (int rr = 0; rr < 2; ++rr) {
    const int r = r0 + rg * 2 + rr;
#pragma unroll
    for (int j = 0; j < 4; ++j)
      Qf[(size_t)r * 64 + ci + 16 * j] = (aq[rr][j] - mqv[j]) * sqv[j] + bqv[j];
    float kv = ak[rr];
    float mx = kv;
#pragma unroll
    for (int d = 1; d < 16; d <<= 1) mx = fmaxf(mx, __shfl_xor(mx, d, 64));
    float e = __expf(kv - mx);
    float sm = e;
#pragma unroll
    for (int d = 1; d < 16; d <<= 1) sm += __shfl_xor(sm, d, 64);
    kout[rr] = e / sm;
#pragma unroll
    for (int j = 0; j < 4; ++j)
      vout[rr][j] = (av[rr][j] - mvv[j]) * svv[j] + bvv[j];
  }

  __syncthreads();
  float* vt = xs;               // [32][65]
  float* ks = xs + 32 * 65;     // [32][20]
#pragma unroll
  for (int rr = 0; rr < 2; ++rr) {
    const int rl = rg * 2 + rr;
    ks[rl * 20 + ci] = kout[rr];
#pragma unroll
    for (int j = 0; j < 4; ++j) vt[rl * 65 + ci + 16 * j] = vout[rr][j];
  }
  __syncthreads();

  {
    const int v = t & 63, grp = t >> 6;
    union { uint16_t u16[8]; uint4 u4; } pk;
#pragma unroll
    for (int i = 0; i < 8; ++i) pk.u16[i] = f2bf(vt[(grp * 8 + i) * 65 + v]);
    *(uint4*)&VbfT[(size_t)(b * 64 + v) * 1024 + mc * 32 + grp * 8] = pk.u4;
  }
  {
    const int kq = t >> 6, v = t & 63;
    float a0 = 0.f, a1 = 0.f, a2 = 0.f, a3 = 0.f;
#pragma unroll 4
    for (int m = 0; m < 32; ++m) {
      float vv = vt[m * 65 + v];
      a0 = fmaf(ks[m * 20 + kq * 4 + 0], vv, a0);
      a1 = fmaf(ks[m * 20 + kq * 4 + 1], vv, a1);
      a2 = fmaf(ks[m * 20 + kq * 4 + 2], vv, a2);
      a3 = fmaf(ks[m * 20 + kq * 4 + 3], vv, a3);
    }
    float* dst = part + ((size_t)(b * 32 + mc) << 10) + (kq * 4) * 64 + v;
    dst[0] = a0; dst[64] = a1; dst[128] = a2; dst[192] = a3;
  }
}

// Kernel 3: reduce 32 partials -> Lc[b][k][v]
__global__ __launch_bounds__(256) void lamc_reduce(const float* __restrict__ part,
                                                   float* __restrict__ Lc)
{
  const int gid = blockIdx.x * 256 + threadIdx.x;   // 0..16383
  const int b = gid >> 10, r = gid & 1023;
  const float* p = part + ((size_t)b << 15) + r;
  float s = 0.f;
#pragma unroll
  for (int mc = 0; mc < 32; ++mc) s += p[mc << 10];
  Lc[((size_t)b << 10) + r] = s;
}

// ---------------------------------------------------------------------------
// Kernel 4: GEMM + fused epilogue. 256x256 tile, BK=64, 8 waves (2x4),
// double buffer, prefetch-before-compute, XOR swizzle, XCD map.
// EPILOGUE FULLY UNROLLED: all acc[] indices compile-time (rule #20 —
// the previous runtime-p index sent acc to scratch: 1.13 GB/dispatch).
// ---------------------------------------------------------------------------
__global__ __launch_bounds__(512, 2) void gemm_out(
    const uint16_t* __restrict__ Ebf,   // [16384][1024]
    const uint16_t* __restrict__ VbfT,  // [1024][1024]
    const float* __restrict__ Qf,       // [16384][64]
    const float* __restrict__ Lc,       // [16][16][64]
    float* __restrict__ out)            // [16384][256]
{
  __shared__ __align__(16) char smem[131072];
  char* const A0 = smem;
  char* const B0 = smem + 32768;
  char* const A1 = smem + 65536;
  char* const B1 = smem + 98304;

  const int t = threadIdx.x;
  const int wid = t >> 6, lane = t & 63;
  const int wm = wid >> 2, wn = wid & 3;
  const int bid = blockIdx.x;
  const int xcd = bid & 7, idx = bid >> 3;
  const int rb = xcd * 8 + (idx >> 2);   // 0..63
  const int cb = idx & 3;                // 0..3
  const int row0 = rb * 256;
  const int col0 = cb * 256;

  const uint16_t* aptr[4];
  const uint16_t* bptr[4];
  int dst[4];
  {
    const uint16_t* Ab = Ebf + ((size_t)row0 << 10);
    const uint16_t* Bb = VbfT + ((size_t)col0 << 10);
#pragma unroll
    for (int it = 0; it < 4; ++it) {
      int id = it * 512 + t;
      int row = id >> 3, seg = id & 7;
      int src = (row << 10) + ((seg ^ (row & 7)) << 3);
      aptr[it] = Ab + src;
      bptr[it] = Bb + src;
      dst[it] = id * 16;
    }
  }

  f32x4 acc[8][4];
#pragma unroll
  for (int i = 0; i < 8; ++i)
#pragma unroll
    for (int j = 0; j < 4; ++j) acc[i][j] = f32x4{0.f, 0.f, 0.f, 0.f};

#pragma unroll
  for (int it = 0; it < 4; ++it) {
    gload_lds16(aptr[it], A0 + dst[it]);
    gload_lds16(bptr[it], B0 + dst[it]);
  }
  __syncthreads();

#pragma unroll 1
  for (int kt = 0; kt < 16; ++kt) {
    char* Ac = (kt & 1) ? A1 : A0;
    char* Bc = (kt & 1) ? B1 : B0;
    char* An = (kt & 1) ? A0 : A1;
    char* Bn = (kt & 1) ? B0 : B1;
    if (kt < 15) {
      const int off = (kt + 1) * 64;
#pragma unroll
      for (int it = 0; it < 4; ++it) {
        gload_lds16(aptr[it] + off, An + dst[it]);
        gload_lds16(bptr[it] + off, Bn + dst[it]);
      }
    }
    __builtin_amdgcn_s_setprio(1);
#pragma unroll
    for (int kk = 0; kk < 2; ++kk) {
      bf16x8 a[8], b[4];
      const int s = kk * 4 + (lane >> 4);
#pragma unroll
      for (int i = 0; i < 8; ++i) {
        int row = wm * 128 + i * 16 + (lane & 15);
        a[i] = *(const bf16x8*)(Ac + row * 128 + ((s ^ (row & 7)) << 4));
      }
#pragma unroll
      for (int j = 0; j < 4; ++j) {
        int row = wn * 64 + j * 16 + (lane & 15);
        b[j] = *(const bf16x8*)(Bc + row * 128 + ((s ^ (row & 7)) << 4));
      }
#pragma unroll
      for (int i = 0; i < 8; ++i)
#pragma unroll
        for (int j = 0; j < 4; ++j)
          acc[i][j] = __builtin_amdgcn_mfma_f32_16x16x32_bf16(a[i], b[j], acc[i][j], 0, 0, 0);
    }
    __builtin_amdgcn_s_setprio(0);
    __syncthreads();
  }

  // fused epilogue: 4 phases of 64 rows through LDS — FULLY UNROLLED so
  // every acc[][] index is a compile-time constant.
  float* Cs = (float*)smem;        // [64][258]
  const int n0 = rb * 16;
  const int b0 = cb * 4;
#pragma unroll
  for (int p = 0; p < 4; ++p) {
    if (wm == (p >> 1)) {
#pragma unroll
      for (int il = 0; il < 4; ++il) {
        const int i = ((p & 1) << 2) + il;
#pragma unroll
        for (int j = 0; j < 4; ++j) {
          const int col = wn * 64 + j * 16 + (lane & 15);
          const int bb = b0 + (col >> 6), v = col & 63;
#pragma unroll
          for (int r = 0; r < 4; ++r) {
            const int rl = il * 16 + ((lane >> 4) << 2) + r;
            const int k = rl & 15;
            Cs[rl * 258 + col] = acc[i][j][r] + Lc[(size_t)(((bb << 4) + k) << 6) + v];
          }
        }
      }
    }
    __syncthreads();
    {
      const int v = t & 63;
#pragma unroll
      for (int c = 0; c < 8; ++c) {
        const int combo = (wid << 3) + c;               // 0..63
        const int n_l = combo >> 4;                     // 0..3
        const int b_l = (combo >> 2) & 3;               // 0..3
        const int h = combo & 3;
        const int n = n0 + (p << 2) + n_l;
        const int bb = b0 + b_l;
        const float* qp = Qf + (((size_t)(bb << 10) + n) << 6) + (h << 4);
        float sum = 0.f;
#pragma unroll
        for (int k = 0; k < 16; ++k)
          sum = fmaf(qp[k], Cs[((n_l << 4) + k) * 258 + (b_l << 6) + v], sum);
        out[(((size_t)(bb << 10) + n) << 8) + (h << 6) + v] = sum;
      }
    }
    __syncthreads();
  }
}

// ---------------------------------------------------------------------------
extern "C" void kernel_launch(void* const* d_in, const int* in_sizes, int n_in,
                              void* d_out, int out_size, void* d_ws, size_t ws_size,
                              hipStream_t stream) {
  const float* x   = (const float*)d_in[0];
  const float* Wq  = (const float*)d_in[1];
  const float* Wk  = (const float*)d_in[2];
  const float* Wv  = (const float*)d_in[3];
  const float* gq  = (const float*)d_in[4];
  const float* bq  = (const float*)d_in[5];
  const float* mq  = (const float*)d_in[6];
  const float* vq  = (const float*)d_in[7];
  const float* gv  = (const float*)d_in[8];
  const float* bv  = (const float*)d_in[9];
  const float* mv  = (const float*)d_in[10];
  const float* vvp = (const float*)d_in[11];
  const float* E   = (const float*)d_in[12];
  float* out = (float*)d_out;

  char* ws = (char*)d_ws;
  uint16_t* Ebf  = (uint16_t*)(ws);                          // 32 MB
  uint16_t* VbfT = (uint16_t*)(ws + 33554432);               //  2 MB
  float*    Qf   = (float*)(ws + 35651584);                  //  4 MB
  float*    part = (float*)(ws + 39845888);                  //  2 MB
  float*    Lc   = (float*)(ws + 41943040);                  // 64 KB

  hipLaunchKernelGGL(econv, dim3(1024), dim3(256), 0, stream, E, Ebf);
  hipLaunchKernelGGL(proj_fused, dim3(512), dim3(256), 0, stream, x, Wq, Wk, Wv,
                     gq, bq, mq, vq, gv, bv, mv, vvp, Qf, VbfT, part);
  hipLaunchKernelGGL(lamc_reduce, dim3(64), dim3(256), 0, stream, part, Lc);
  hipLaunchKernelGGL(gemm_out, dim3(256), dim3(512), 0, stream, Ebf, VbfT, Qf, Lc, out);
}

// Round 5
// 83.585 us; speedup vs baseline: 3.3677x; 1.4404x over previous
//
#include <hip/hip_runtime.h>
#include <stdint.h>

#define EPS 1e-3f

typedef __bf16 bf16x8 __attribute__((ext_vector_type(8)));
typedef float  f32x4  __attribute__((ext_vector_type(4)));

static __device__ __forceinline__ uint16_t f2bf(float f) {
  union { float f; uint32_t u; } v; v.f = f;
  uint32_t u = v.u;
  uint32_t r = u + 0x7fffu + ((u >> 16) & 1u);   // RNE
  return (uint16_t)(r >> 16);
}
static __device__ __forceinline__ void gload_lds16(const void* g, void* l) {
  __builtin_amdgcn_global_load_lds(
      (const __attribute__((address_space(1))) unsigned int*)g,
      (__attribute__((address_space(3))) unsigned int*)l, 16, 0, 0);
}

// ---------------------------------------------------------------------------
// Kernel 1: E convert+transpose (E:[n][m][16] f32 -> Ebf:[n*16+k][m] bf16),
// plus (first 144 blocks) the W transpose/convert prep:
//   WtP[col][k] bf16, row stride 264 (+8 pad) — col 0..63 = Wq, 64..79 = Wk,
//   80..143 = Wv.
// ---------------------------------------------------------------------------
__global__ __launch_bounds__(256) void econv(
    const float* __restrict__ E, uint16_t* __restrict__ Ebf,
    const float* __restrict__ Wq, const float* __restrict__ Wk,
    const float* __restrict__ Wv, uint16_t* __restrict__ WtP)
{
  const int n = blockIdx.x, t = threadIdx.x;
  if (n < 144) {
    const int col = n;   // thread t = k index
    float val = (col < 64) ? Wq[t * 64 + col]
              : (col < 80) ? Wk[t * 16 + (col - 64)]
                           : Wv[t * 64 + (col - 80)];
    WtP[col * 264 + t] = f2bf(val);
  }
  const float* En = E + (size_t)n * 16384;
#pragma unroll 1
  for (int kq = 0; kq < 4; ++kq) {
#pragma unroll
    for (int mi = 0; mi < 4; ++mi) {
      int m = mi * 256 + t;
      float4 d = *(const float4*)&En[m * 16 + kq * 4];
      const float* dp = (const float*)&d;
#pragma unroll
      for (int j = 0; j < 4; ++j) {
        int k = kq * 4 + j;
        Ebf[(size_t)(n * 16 + k) * 1024 + m] = f2bf(dp[j]);
      }
    }
  }
}

// ---------------------------------------------------------------------------
// Kernel 2: MFMA projections + BN + softmax + V-transpose + lam_c partial.
// 256 blocks (1/CU) x 256 threads (4 waves). Block = 64 rows (batch b,
// m-chunk mc of 64). out[row][col0..143] = x[row][:] @ W[:, col] via
// 16x16x32 bf16 MFMA; W from WtP (gload_lds), x reg-staged fp32->bf16.
// ---------------------------------------------------------------------------
__global__ __launch_bounds__(256) void proj_mfma(
    const float* __restrict__ x, const uint16_t* __restrict__ WtP,
    const float* __restrict__ gq, const float* __restrict__ bq,
    const float* __restrict__ mq, const float* __restrict__ vq,
    const float* __restrict__ gv, const float* __restrict__ bv,
    const float* __restrict__ mv, const float* __restrict__ vvp,
    float* __restrict__ Qf, uint16_t* __restrict__ VbfT,
    float* __restrict__ part)
{
  __shared__ __align__(16) char smem[111616];   // xA 33792 + Wt 77824
  uint16_t* const xA = (uint16_t*)smem;         // [64][264] bf16 (528 B rows)
  char* const Wt = smem + 33792;                // [144][264] bf16 (+ tail pad)

  const int t = threadIdx.x;
  const int wid = t >> 6, lane = t & 63;
  const int bid = blockIdx.x;
  const int b = bid >> 4, mc = bid & 15;
  const int r0 = b * 1024 + mc * 64;

  // stage Wt (76 KB + pad) via global_load_lds: 19 chunks of 16B per thread
#pragma unroll
  for (int i = 0; i < 19; ++i) {
    int off = (i * 256 + t) * 16;
    gload_lds16((const char*)WtP + off, Wt + off);
  }
  // stage x tile: 64 rows x 256 k, fp32 -> bf16, padded rows
  {
    const int row = t >> 2, ks0 = (t & 3) * 64;
    const float* src = x + (size_t)(r0 + row) * 256 + ks0;
    uint16_t* dstp = xA + row * 264 + ks0;
#pragma unroll
    for (int i = 0; i < 8; ++i) {
      float4 d0 = *(const float4*)(src + i * 8);
      float4 d1 = *(const float4*)(src + i * 8 + 4);
      union { uint16_t u[8]; uint4 q; } pk;
      pk.u[0] = f2bf(d0.x); pk.u[1] = f2bf(d0.y);
      pk.u[2] = f2bf(d0.z); pk.u[3] = f2bf(d0.w);
      pk.u[4] = f2bf(d1.x); pk.u[5] = f2bf(d1.y);
      pk.u[6] = f2bf(d1.z); pk.u[7] = f2bf(d1.w);
      *(uint4*)(dstp + i * 8) = pk.q;
    }
  }
  __syncthreads();

  // MFMA: wave wid owns rows [wid*16, wid*16+16), all 144 cols (9 frags)
  f32x4 acc[9];
#pragma unroll
  for (int f = 0; f < 9; ++f) acc[f] = f32x4{0.f, 0.f, 0.f, 0.f};
  const int arow = wid * 16 + (lane & 15);
#pragma unroll
  for (int kst = 0; kst < 8; ++kst) {
    const int sb = kst * 64 + ((lane >> 4) << 4);
    bf16x8 af = *(const bf16x8*)((const char*)xA + arow * 528 + sb);
#pragma unroll
    for (int f = 0; f < 9; ++f) {
      const int crow = f * 16 + (lane & 15);
      bf16x8 bfr = *(const bf16x8*)(Wt + crow * 528 + sb);
      acc[f] = __builtin_amdgcn_mfma_f32_16x16x32_bf16(af, bfr, acc[f], 0, 0, 0);
    }
  }

  // epilogue: C layout col = lane&15, row = wid*16 + (lane>>4)*4 + r
  const int cl = lane & 15;
  const int rbase = wid * 16 + ((lane >> 4) << 2);

  float qs[4], qb[4], qm[4], vs[4], vb[4], vm[4];
#pragma unroll
  for (int f = 0; f < 4; ++f) {
    const int c = f * 16 + cl;
    qs[f] = gq[c] * rsqrtf(vq[c] + EPS); qb[f] = bq[c]; qm[f] = mq[c];
    vs[f] = gv[c] * rsqrtf(vvp[c] + EPS); vb[f] = bv[c]; vm[f] = mv[c];
  }
  // Qf (fp32, BN applied)
#pragma unroll
  for (int f = 0; f < 4; ++f)
#pragma unroll
    for (int r = 0; r < 4; ++r)
      Qf[(size_t)(r0 + rbase + r) * 64 + f * 16 + cl] =
          (acc[f][r] - qm[f]) * qs[f] + qb[f];
  // softmax over the 16 k-channels (lanes cl=0..15 within each quarter-wave)
  float ex[4];
#pragma unroll
  for (int r = 0; r < 4; ++r) {
    float kv = acc[4][r];
    float mx = kv;
#pragma unroll
    for (int d = 1; d < 16; d <<= 1) mx = fmaxf(mx, __shfl_xor(mx, d, 64));
    float e = __expf(kv - mx);
    float sm = e;
#pragma unroll
    for (int d = 1; d < 16; d <<= 1) sm += __shfl_xor(sm, d, 64);
    ex[r] = e / sm;
  }
  // v with BN -> regs
  float vv[4][4];
#pragma unroll
  for (int f = 0; f < 4; ++f)
#pragma unroll
    for (int r = 0; r < 4; ++r)
      vv[f][r] = (acc[5 + f][r] - vm[f]) * vs[f] + vb[f];

  __syncthreads();   // done reading xA/Wt
  float* const vt = (float*)smem;                 // [64][65] f32
  float* const ks = (float*)(smem + 64 * 65 * 4); // [64][20] f32
#pragma unroll
  for (int r = 0; r < 4; ++r) ks[(rbase + r) * 20 + cl] = ex[r];
#pragma unroll
  for (int f = 0; f < 4; ++f)
#pragma unroll
    for (int r = 0; r < 4; ++r) vt[(rbase + r) * 65 + f * 16 + cl] = vv[f][r];
  __syncthreads();

  // V transpose -> VbfT[b*64+v][m], 16 m's per thread (2x b128)
  {
    const int v = t & 63, grp = t >> 6;
#pragma unroll
    for (int h = 0; h < 2; ++h) {
      union { uint16_t u16[8]; uint4 q; } pk;
#pragma unroll
      for (int i = 0; i < 8; ++i)
        pk.u16[i] = f2bf(vt[(grp * 16 + h * 8 + i) * 65 + v]);
      *(uint4*)&VbfT[(size_t)(b * 64 + v) * 1024 + mc * 64 + grp * 16 + h * 8] = pk.q;
    }
  }
  // lam_c partial over this 64-m chunk
  {
    const int kq = t >> 6, v = t & 63;
    float a0 = 0.f, a1 = 0.f, a2 = 0.f, a3 = 0.f;
#pragma unroll 4
    for (int m = 0; m < 64; ++m) {
      float vvx = vt[m * 65 + v];
      a0 = fmaf(ks[m * 20 + kq * 4 + 0], vvx, a0);
      a1 = fmaf(ks[m * 20 + kq * 4 + 1], vvx, a1);
      a2 = fmaf(ks[m * 20 + kq * 4 + 2], vvx, a2);
      a3 = fmaf(ks[m * 20 + kq * 4 + 3], vvx, a3);
    }
    float* dst = part + ((size_t)(b * 16 + mc) << 10) + (kq * 4) * 64 + v;
    dst[0] = a0; dst[64] = a1; dst[128] = a2; dst[192] = a3;
  }
}

// Kernel 3: reduce 16 partials -> Lc[b][k][v]
__global__ __launch_bounds__(256) void lamc_reduce(const float* __restrict__ part,
                                                   float* __restrict__ Lc)
{
  const int gid = blockIdx.x * 256 + threadIdx.x;   // 0..16383
  const int b = gid >> 10, r = gid & 1023;
  const float* p = part + ((size_t)b << 14) + r;
  float s = 0.f;
#pragma unroll
  for (int mc = 0; mc < 16; ++mc) s += p[mc << 10];
  Lc[((size_t)b << 10) + r] = s;
}

// ---------------------------------------------------------------------------
// Kernel 4: GEMM + fused epilogue (unchanged from round 4 — passing).
// ---------------------------------------------------------------------------
__global__ __launch_bounds__(512, 2) void gemm_out(
    const uint16_t* __restrict__ Ebf,   // [16384][1024]
    const uint16_t* __restrict__ VbfT,  // [1024][1024]
    const float* __restrict__ Qf,       // [16384][64]
    const float* __restrict__ Lc,       // [16][16][64]
    float* __restrict__ out)            // [16384][256]
{
  __shared__ __align__(16) char smem[131072];
  char* const A0 = smem;
  char* const B0 = smem + 32768;
  char* const A1 = smem + 65536;
  char* const B1 = smem + 98304;

  const int t = threadIdx.x;
  const int wid = t >> 6, lane = t & 63;
  const int wm = wid >> 2, wn = wid & 3;
  const int bid = blockIdx.x;
  const int xcd = bid & 7, idx = bid >> 3;
  const int rb = xcd * 8 + (idx >> 2);   // 0..63
  const int cb = idx & 3;                // 0..3
  const int row0 = rb * 256;
  const int col0 = cb * 256;

  const uint16_t* aptr[4];
  const uint16_t* bptr[4];
  int dst[4];
  {
    const uint16_t* Ab = Ebf + ((size_t)row0 << 10);
    const uint16_t* Bb = VbfT + ((size_t)col0 << 10);
#pragma unroll
    for (int it = 0; it < 4; ++it) {
      int id = it * 512 + t;
      int row = id >> 3, seg = id & 7;
      int src = (row << 10) + ((seg ^ (row & 7)) << 3);
      aptr[it] = Ab + src;
      bptr[it] = Bb + src;
      dst[it] = id * 16;
    }
  }

  f32x4 acc[8][4];
#pragma unroll
  for (int i = 0; i < 8; ++i)
#pragma unroll
    for (int j = 0; j < 4; ++j) acc[i][j] = f32x4{0.f, 0.f, 0.f, 0.f};

#pragma unroll
  for (int it = 0; it < 4; ++it) {
    gload_lds16(aptr[it], A0 + dst[it]);
    gload_lds16(bptr[it], B0 + dst[it]);
  }
  __syncthreads();

#pragma unroll 1
  for (int kt = 0; kt < 16; ++kt) {
    char* Ac = (kt & 1) ? A1 : A0;
    char* Bc = (kt & 1) ? B1 : B0;
    char* An = (kt & 1) ? A0 : A1;
    char* Bn = (kt & 1) ? B0 : B1;
    if (kt < 15) {
      const int off = (kt + 1) * 64;
#pragma unroll
      for (int it = 0; it < 4; ++it) {
        gload_lds16(aptr[it] + off, An + dst[it]);
        gload_lds16(bptr[it] + off, Bn + dst[it]);
      }
    }
    __builtin_amdgcn_s_setprio(1);
#pragma unroll
    for (int kk = 0; kk < 2; ++kk) {
      bf16x8 a[8], b[4];
      const int s = kk * 4 + (lane >> 4);
#pragma unroll
      for (int i = 0; i < 8; ++i) {
        int row = wm * 128 + i * 16 + (lane & 15);
        a[i] = *(const bf16x8*)(Ac + row * 128 + ((s ^ (row & 7)) << 4));
      }
#pragma unroll
      for (int j = 0; j < 4; ++j) {
        int row = wn * 64 + j * 16 + (lane & 15);
        b[j] = *(const bf16x8*)(Bc + row * 128 + ((s ^ (row & 7)) << 4));
      }
#pragma unroll
      for (int i = 0; i < 8; ++i)
#pragma unroll
        for (int j = 0; j < 4; ++j)
          acc[i][j] = __builtin_amdgcn_mfma_f32_16x16x32_bf16(a[i], b[j], acc[i][j], 0, 0, 0);
    }
    __builtin_amdgcn_s_setprio(0);
    __syncthreads();
  }

  float* Cs = (float*)smem;        // [64][258]
  const int n0 = rb * 16;
  const int b0 = cb * 4;
#pragma unroll
  for (int p = 0; p < 4; ++p) {
    if (wm == (p >> 1)) {
#pragma unroll
      for (int il = 0; il < 4; ++il) {
        const int i = ((p & 1) << 2) + il;
#pragma unroll
        for (int j = 0; j < 4; ++j) {
          const int col = wn * 64 + j * 16 + (lane & 15);
          const int bb = b0 + (col >> 6), v = col & 63;
#pragma unroll
          for (int r = 0; r < 4; ++r) {
            const int rl = il * 16 + ((lane >> 4) << 2) + r;
            const int k = rl & 15;
            Cs[rl * 258 + col] = acc[i][j][r] + Lc[(size_t)(((bb << 4) + k) << 6) + v];
          }
        }
      }
    }
    __syncthreads();
    {
      const int v = t & 63;
#pragma unroll
      for (int c = 0; c < 8; ++c) {
        const int combo = (wid << 3) + c;               // 0..63
        const int n_l = combo >> 4;                     // 0..3
        const int b_l = (combo >> 2) & 3;               // 0..3
        const int h = combo & 3;
        const int n = n0 + (p << 2) + n_l;
        const int bb = b0 + b_l;
        const float* qp = Qf + (((size_t)(bb << 10) + n) << 6) + (h << 4);
        float sum = 0.f;
#pragma unroll
        for (int k = 0; k < 16; ++k)
          sum = fmaf(qp[k], Cs[((n_l << 4) + k) * 258 + (b_l << 6) + v], sum);
        out[(((size_t)(bb << 10) + n) << 8) + (h << 6) + v] = sum;
      }
    }
    __syncthreads();
  }
}

// ---------------------------------------------------------------------------
extern "C" void kernel_launch(void* const* d_in, const int* in_sizes, int n_in,
                              void* d_out, int out_size, void* d_ws, size_t ws_size,
                              hipStream_t stream) {
  const float* x   = (const float*)d_in[0];
  const float* Wq  = (const float*)d_in[1];
  const float* Wk  = (const float*)d_in[2];
  const float* Wv  = (const float*)d_in[3];
  const float* gq  = (const float*)d_in[4];
  const float* bq  = (const float*)d_in[5];
  const float* mq  = (const float*)d_in[6];
  const float* vq  = (const float*)d_in[7];
  const float* gv  = (const float*)d_in[8];
  const float* bv  = (const float*)d_in[9];
  const float* mv  = (const float*)d_in[10];
  const float* vvp = (const float*)d_in[11];
  const float* E   = (const float*)d_in[12];
  float* out = (float*)d_out;

  char* ws = (char*)d_ws;
  uint16_t* Ebf  = (uint16_t*)(ws);                          // 32 MB
  uint16_t* VbfT = (uint16_t*)(ws + 33554432);               //  2 MB
  float*    Qf   = (float*)(ws + 35651584);                  //  4 MB
  float*    part = (float*)(ws + 39845888);                  //  1 MB
  float*    Lc   = (float*)(ws + 40894464);                  // 64 KB
  uint16_t* WtP  = (uint16_t*)(ws + 40960000);               // 77,824 B

  hipLaunchKernelGGL(econv, dim3(1024), dim3(256), 0, stream,
                     E, Ebf, Wq, Wk, Wv, WtP);
  hipLaunchKernelGGL(proj_mfma, dim3(256), dim3(256), 0, stream, x, WtP,
                     gq, bq, mq, vq, gv, bv, mv, vvp, Qf, VbfT, part);
  hipLaunchKernelGGL(lamc_reduce, dim3(64), dim3(256), 0, stream, part, Lc);
  hipLaunchKernelGGL(gemm_out, dim3(256), dim3(512), 0, stream, Ebf, VbfT, Qf, Lc, out);
}

// Round 6
// 75.384 us; speedup vs baseline: 3.7340x; 1.1088x over previous
//
#include <hip/hip_runtime.h>
#include <stdint.h>

#define EPS 1e-3f

typedef __bf16 bf16x8 __attribute__((ext_vector_type(8)));
typedef float  f32x4  __attribute__((ext_vector_type(4)));

static __device__ __forceinline__ uint16_t f2bf(float f) {
  union { float f; uint32_t u; } v; v.f = f;
  uint32_t u = v.u;
  uint32_t r = u + 0x7fffu + ((u >> 16) & 1u);   // RNE
  return (uint16_t)(r >> 16);
}
static __device__ __forceinline__ uint32_t pack2bf(float lo, float hi) {
  union { uint16_t h[2]; uint32_t u; } r;
  r.h[0] = f2bf(lo); r.h[1] = f2bf(hi);
  return r.u;
}
static __device__ __forceinline__ void gload_lds16(const void* g, void* l) {
  __builtin_amdgcn_global_load_lds(
      (const __attribute__((address_space(1))) unsigned int*)g,
      (__attribute__((address_space(3))) unsigned int*)l, 16, 0, 0);
}

// ---------------------------------------------------------------------------
// Kernel 0: W transpose/convert prep (tiny).
// WtP[col][k] bf16, row stride 264; col 0..63 = Wq, 64..79 = Wk, 80..143 = Wv.
// ---------------------------------------------------------------------------
__global__ __launch_bounds__(256) void wprep(
    const float* __restrict__ Wq, const float* __restrict__ Wk,
    const float* __restrict__ Wv, uint16_t* __restrict__ WtP)
{
  const int col = blockIdx.x, t = threadIdx.x;
  float val = (col < 64) ? Wq[t * 64 + col]
            : (col < 80) ? Wk[t * 16 + (col - 64)]
                         : Wv[t * 64 + (col - 80)];
  WtP[col * 264 + t] = f2bf(val);
}

// ---------------------------------------------------------------------------
// Kernel 1: MFMA projections + BN + softmax + V-transpose + lam_c partial.
// (unchanged from round 5 — passing, off the critical top-5)
// ---------------------------------------------------------------------------
__global__ __launch_bounds__(256) void proj_mfma(
    const float* __restrict__ x, const uint16_t* __restrict__ WtP,
    const float* __restrict__ gq, const float* __restrict__ bq,
    const float* __restrict__ mq, const float* __restrict__ vq,
    const float* __restrict__ gv, const float* __restrict__ bv,
    const float* __restrict__ mv, const float* __restrict__ vvp,
    float* __restrict__ Qf, uint16_t* __restrict__ VbfT,
    float* __restrict__ part)
{
  __shared__ __align__(16) char smem[111616];   // xA 33792 + Wt 77824
  uint16_t* const xA = (uint16_t*)smem;         // [64][264] bf16 (528 B rows)
  char* const Wt = smem + 33792;                // [144][264] bf16

  const int t = threadIdx.x;
  const int wid = t >> 6, lane = t & 63;
  const int bid = blockIdx.x;
  const int b = bid >> 4, mc = bid & 15;
  const int r0 = b * 1024 + mc * 64;

#pragma unroll
  for (int i = 0; i < 19; ++i) {
    int off = (i * 256 + t) * 16;
    gload_lds16((const char*)WtP + off, Wt + off);
  }
  {
    const int row = t >> 2, ks0 = (t & 3) * 64;
    const float* src = x + (size_t)(r0 + row) * 256 + ks0;
    uint16_t* dstp = xA + row * 264 + ks0;
#pragma unroll
    for (int i = 0; i < 8; ++i) {
      float4 d0 = *(const float4*)(src + i * 8);
      float4 d1 = *(const float4*)(src + i * 8 + 4);
      union { uint16_t u[8]; uint4 q; } pk;
      pk.u[0] = f2bf(d0.x); pk.u[1] = f2bf(d0.y);
      pk.u[2] = f2bf(d0.z); pk.u[3] = f2bf(d0.w);
      pk.u[4] = f2bf(d1.x); pk.u[5] = f2bf(d1.y);
      pk.u[6] = f2bf(d1.z); pk.u[7] = f2bf(d1.w);
      *(uint4*)(dstp + i * 8) = pk.q;
    }
  }
  __syncthreads();

  f32x4 acc[9];
#pragma unroll
  for (int f = 0; f < 9; ++f) acc[f] = f32x4{0.f, 0.f, 0.f, 0.f};
  const int arow = wid * 16 + (lane & 15);
#pragma unroll
  for (int kst = 0; kst < 8; ++kst) {
    const int sb = kst * 64 + ((lane >> 4) << 4);
    bf16x8 af = *(const bf16x8*)((const char*)xA + arow * 528 + sb);
#pragma unroll
    for (int f = 0; f < 9; ++f) {
      const int crow = f * 16 + (lane & 15);
      bf16x8 bfr = *(const bf16x8*)(Wt + crow * 528 + sb);
      acc[f] = __builtin_amdgcn_mfma_f32_16x16x32_bf16(af, bfr, acc[f], 0, 0, 0);
    }
  }

  const int cl = lane & 15;
  const int rbase = wid * 16 + ((lane >> 4) << 2);

  float qs[4], qb[4], qm[4], vs[4], vb[4], vm[4];
#pragma unroll
  for (int f = 0; f < 4; ++f) {
    const int c = f * 16 + cl;
    qs[f] = gq[c] * rsqrtf(vq[c] + EPS); qb[f] = bq[c]; qm[f] = mq[c];
    vs[f] = gv[c] * rsqrtf(vvp[c] + EPS); vb[f] = bv[c]; vm[f] = mv[c];
  }
#pragma unroll
  for (int f = 0; f < 4; ++f)
#pragma unroll
    for (int r = 0; r < 4; ++r)
      Qf[(size_t)(r0 + rbase + r) * 64 + f * 16 + cl] =
          (acc[f][r] - qm[f]) * qs[f] + qb[f];
  float ex[4];
#pragma unroll
  for (int r = 0; r < 4; ++r) {
    float kv = acc[4][r];
    float mx = kv;
#pragma unroll
    for (int d = 1; d < 16; d <<= 1) mx = fmaxf(mx, __shfl_xor(mx, d, 64));
    float e = __expf(kv - mx);
    float sm = e;
#pragma unroll
    for (int d = 1; d < 16; d <<= 1) sm += __shfl_xor(sm, d, 64);
    ex[r] = e / sm;
  }
  float vv[4][4];
#pragma unroll
  for (int f = 0; f < 4; ++f)
#pragma unroll
    for (int r = 0; r < 4; ++r)
      vv[f][r] = (acc[5 + f][r] - vm[f]) * vs[f] + vb[f];

  __syncthreads();
  float* const vt = (float*)smem;                 // [64][65] f32
  float* const ks = (float*)(smem + 64 * 65 * 4); // [64][20] f32
#pragma unroll
  for (int r = 0; r < 4; ++r) ks[(rbase + r) * 20 + cl] = ex[r];
#pragma unroll
  for (int f = 0; f < 4; ++f)
#pragma unroll
    for (int r = 0; r < 4; ++r) vt[(rbase + r) * 65 + f * 16 + cl] = vv[f][r];
  __syncthreads();

  {
    const int v = t & 63, grp = t >> 6;
#pragma unroll
    for (int h = 0; h < 2; ++h) {
      union { uint16_t u16[8]; uint4 q; } pk;
#pragma unroll
      for (int i = 0; i < 8; ++i)
        pk.u16[i] = f2bf(vt[(grp * 16 + h * 8 + i) * 65 + v]);
      *(uint4*)&VbfT[(size_t)(b * 64 + v) * 1024 + mc * 64 + grp * 16 + h * 8] = pk.q;
    }
  }
  {
    const int kq = t >> 6, v = t & 63;
    float a0 = 0.f, a1 = 0.f, a2 = 0.f, a3 = 0.f;
#pragma unroll 4
    for (int m = 0; m < 64; ++m) {
      float vvx = vt[m * 65 + v];
      a0 = fmaf(ks[m * 20 + kq * 4 + 0], vvx, a0);
      a1 = fmaf(ks[m * 20 + kq * 4 + 1], vvx, a1);
      a2 = fmaf(ks[m * 20 + kq * 4 + 2], vvx, a2);
      a3 = fmaf(ks[m * 20 + kq * 4 + 3], vvx, a3);
    }
    float* dst = part + ((size_t)(b * 16 + mc) << 10) + (kq * 4) * 64 + v;
    dst[0] = a0; dst[64] = a1; dst[128] = a2; dst[192] = a3;
  }
}

// Kernel 2: reduce 16 partials -> Lc[b][k][v]
__global__ __launch_bounds__(256) void lamc_reduce(const float* __restrict__ part,
                                                   float* __restrict__ Lc)
{
  const int gid = blockIdx.x * 256 + threadIdx.x;   // 0..16383
  const int b = gid >> 10, r = gid & 1023;
  const float* p = part + ((size_t)b << 14) + r;
  float s = 0.f;
#pragma unroll
  for (int mc = 0; mc < 16; ++mc) s += p[mc << 10];
  Lc[((size_t)b << 10) + r] = s;
}

// ---------------------------------------------------------------------------
// Kernel 3: GEMM + fused epilogue. A is reg-staged DIRECTLY from E (fp32 ->
// bf16 pack -> swizzled ds_write, T14 split: loads before MFMA, writes after).
// B staged by global_load_lds. 256x256 tile, BK=64, 8 waves (2x4), double
// buffer, one barrier/tile, XOR swizzle, XCD map. Epilogue fully unrolled.
// ---------------------------------------------------------------------------
__global__ __launch_bounds__(512, 2) void gemm_out(
    const float* __restrict__ E,        // [1024 n][1024 m][16 k] f32
    const uint16_t* __restrict__ VbfT,  // [1024 col][1024 m] bf16
    const float* __restrict__ Qf,       // [16384][64]
    const float* __restrict__ Lc,       // [16][16][64]
    float* __restrict__ out)            // [16384][256]
{
  __shared__ __align__(16) char smem[131072];
  char* const A0 = smem;
  char* const B0 = smem + 32768;
  char* const A1 = smem + 65536;
  char* const B1 = smem + 98304;

  const int t = threadIdx.x;
  const int wid = t >> 6, lane = t & 63;
  const int wm = wid >> 2, wn = wid & 3;
  const int bid = blockIdx.x;
  const int xcd = bid & 7, idx = bid >> 3;
  const int rb = xcd * 8 + (idx >> 2);   // 0..63
  const int cb = idx & 3;                // 0..3
  const int col0 = cb * 256;
  const int n0 = rb * 16;

  // A staging: thread -> (k-quad, m-pair, n-group)
  const int kq = t & 3;          // k*4 quad
  const int mp = (t >> 2) & 31;  // m-pair 0..31
  const int nb = t >> 7;         // 0..3
  const float* Eb = E + ((size_t)n0 << 14);

  // A ds_write byte offsets (4 its x 4 j), compile-time-indexed
  int awoff[4][4];
#pragma unroll
  for (int it = 0; it < 4; ++it)
#pragma unroll
    for (int j = 0; j < 4; ++j) {
      int row = (it * 4 + nb) * 16 + kq * 4 + j;
      awoff[it][j] = row * 128 + ((mp * 4) ^ ((row & 7) << 4));
    }

  // B staging pointers
  const uint16_t* bptr[4];
  int bdst[4];
  {
    const uint16_t* Bb = VbfT + ((size_t)col0 << 10);
#pragma unroll
    for (int it = 0; it < 4; ++it) {
      int id = it * 512 + t;
      int row = id >> 3, seg = id & 7;
      bptr[it] = Bb + (row << 10) + ((seg ^ (row & 7)) << 3);
      bdst[it] = id * 16;
    }
  }

  f32x4 acc[8][4];
#pragma unroll
  for (int i = 0; i < 8; ++i)
#pragma unroll
    for (int j = 0; j < 4; ++j) acc[i][j] = f32x4{0.f, 0.f, 0.f, 0.f};

  float4 ra[4], rbx[4];

  // ---- prologue: tile 0 ----
#pragma unroll
  for (int it = 0; it < 4; ++it) {
    size_t base = ((size_t)(it * 4 + nb) << 14) + ((size_t)(mp * 2) << 4) + (kq << 2);
    ra[it]  = *(const float4*)(Eb + base);
    rbx[it] = *(const float4*)(Eb + base + 16);
  }
#pragma unroll
  for (int it = 0; it < 4; ++it) gload_lds16(bptr[it], B0 + bdst[it]);
#pragma unroll
  for (int it = 0; it < 4; ++it) {
    const float* da = (const float*)&ra[it];
    const float* db = (const float*)&rbx[it];
#pragma unroll
    for (int j = 0; j < 4; ++j)
      *(uint32_t*)(A0 + awoff[it][j]) = pack2bf(da[j], db[j]);
  }
  __syncthreads();

  // ---- main loop: 16 K-tiles of 64 ----
#pragma unroll 1
  for (int kt = 0; kt < 16; ++kt) {
    char* Ac = (kt & 1) ? A1 : A0;
    char* Bc = (kt & 1) ? B1 : B0;
    char* An = (kt & 1) ? A0 : A1;
    char* Bn = (kt & 1) ? B0 : B1;
    if (kt < 15) {
      const int m0n = (kt + 1) * 64;
#pragma unroll
      for (int it = 0; it < 4; ++it) {
        size_t base = ((size_t)(it * 4 + nb) << 14) +
                      ((size_t)(m0n + mp * 2) << 4) + (kq << 2);
        ra[it]  = *(const float4*)(Eb + base);
        rbx[it] = *(const float4*)(Eb + base + 16);
      }
#pragma unroll
      for (int it = 0; it < 4; ++it) gload_lds16(bptr[it] + m0n, Bn + bdst[it]);
    }
    __builtin_amdgcn_s_setprio(1);
#pragma unroll
    for (int kk = 0; kk < 2; ++kk) {
      bf16x8 a[8], b[4];
      const int s = kk * 4 + (lane >> 4);
#pragma unroll
      for (int i = 0; i < 8; ++i) {
        int row = wm * 128 + i * 16 + (lane & 15);
        a[i] = *(const bf16x8*)(Ac + row * 128 + ((s ^ (row & 7)) << 4));
      }
#pragma unroll
      for (int j = 0; j < 4; ++j) {
        int row = wn * 64 + j * 16 + (lane & 15);
        b[j] = *(const bf16x8*)(Bc + row * 128 + ((s ^ (row & 7)) << 4));
      }
#pragma unroll
      for (int i = 0; i < 8; ++i)
#pragma unroll
        for (int j = 0; j < 4; ++j)
          acc[i][j] = __builtin_amdgcn_mfma_f32_16x16x32_bf16(a[i], b[j], acc[i][j], 0, 0, 0);
    }
    __builtin_amdgcn_s_setprio(0);
    if (kt < 15) {
#pragma unroll
      for (int it = 0; it < 4; ++it) {
        const float* da = (const float*)&ra[it];
        const float* db = (const float*)&rbx[it];
#pragma unroll
        for (int j = 0; j < 4; ++j)
          *(uint32_t*)(An + awoff[it][j]) = pack2bf(da[j], db[j]);
      }
    }
    __syncthreads();
  }

  // ---- fused epilogue: 4 phases of 64 rows through LDS, fully unrolled ----
  float* Cs = (float*)smem;        // [64][258]
  const int b0 = cb * 4;
#pragma unroll
  for (int p = 0; p < 4; ++p) {
    if (wm == (p >> 1)) {
#pragma unroll
      for (int il = 0; il < 4; ++il) {
        const int i = ((p & 1) << 2) + il;
#pragma unroll
        for (int j = 0; j < 4; ++j) {
          const int col = wn * 64 + j * 16 + (lane & 15);
          const int bb = b0 + (col >> 6), v = col & 63;
#pragma unroll
          for (int r = 0; r < 4; ++r) {
            const int rl = il * 16 + ((lane >> 4) << 2) + r;
            const int k = rl & 15;
            Cs[rl * 258 + col] = acc[i][j][r] + Lc[(size_t)(((bb << 4) + k) << 6) + v];
          }
        }
      }
    }
    __syncthreads();
    {
      const int v = t & 63;
#pragma unroll
      for (int c = 0; c < 8; ++c) {
        const int combo = (wid << 3) + c;               // 0..63
        const int n_l = combo >> 4;                     // 0..3
        const int b_l = (combo >> 2) & 3;               // 0..3
        const int h = combo & 3;
        const int n = n0 + (p << 2) + n_l;
        const int bb = b0 + b_l;
        const float* qp = Qf + (((size_t)(bb << 10) + n) << 6) + (h << 4);
        float sum = 0.f;
#pragma unroll
        for (int k = 0; k < 16; ++k)
          sum = fmaf(qp[k], Cs[((n_l << 4) + k) * 258 + (b_l << 6) + v], sum);
        out[(((size_t)(bb << 10) + n) << 8) + (h << 6) + v] = sum;
      }
    }
    __syncthreads();
  }
}

// ---------------------------------------------------------------------------
extern "C" void kernel_launch(void* const* d_in, const int* in_sizes, int n_in,
                              void* d_out, int out_size, void* d_ws, size_t ws_size,
                              hipStream_t stream) {
  const float* x   = (const float*)d_in[0];
  const float* Wq  = (const float*)d_in[1];
  const float* Wk  = (const float*)d_in[2];
  const float* Wv  = (const float*)d_in[3];
  const float* gq  = (const float*)d_in[4];
  const float* bq  = (const float*)d_in[5];
  const float* mq  = (const float*)d_in[6];
  const float* vq  = (const float*)d_in[7];
  const float* gv  = (const float*)d_in[8];
  const float* bv  = (const float*)d_in[9];
  const float* mv  = (const float*)d_in[10];
  const float* vvp = (const float*)d_in[11];
  const float* E   = (const float*)d_in[12];
  float* out = (float*)d_out;

  char* ws = (char*)d_ws;
  uint16_t* VbfT = (uint16_t*)(ws);                          //  2 MB
  float*    Qf   = (float*)(ws + (size_t)(2 << 20));         //  4 MB
  float*    part = (float*)(ws + (size_t)(6 << 20));         //  1 MB
  float*    Lc   = (float*)(ws + (size_t)(7 << 20));         // 64 KB
  uint16_t* WtP  = (uint16_t*)(ws + (size_t)(7 << 20) + 65536); // 76 KB

  hipLaunchKernelGGL(wprep, dim3(144), dim3(256), 0, stream, Wq, Wk, Wv, WtP);
  hipLaunchKernelGGL(proj_mfma, dim3(256), dim3(256), 0, stream, x, WtP,
                     gq, bq, mq, vq, gv, bv, mv, vvp, Qf, VbfT, part);
  hipLaunchKernelGGL(lamc_reduce, dim3(64), dim3(256), 0, stream, part, Lc);
  hipLaunchKernelGGL(gemm_out, dim3(256), dim3(512), 0, stream, E, VbfT, Qf, Lc, out);
}